// Round 9
// baseline (54.186 us; speedup 1.0000x reference)
//
#include <hip/hip_runtime.h>
#include <cstdint>
#include <cstddef>

typedef unsigned long long u64;
typedef unsigned int u32;

// Problem constants (from reference)
constexpr int N    = 50000;   // library size
constexpr int D    = 768;     // vision dim
constexpr int OD   = 384;     // option / answer dim
constexpr int TOPK = 25;

// Fused kernel geometry: 1024 blocks x 512 threads (8 waves/block).
// Same wave->row mapping as the proven k_scores (8192 waves total).
constexpr int BLOCKS  = 1024;
constexpr int THREADS = 512;
constexpr int WPB     = THREADS / 64;          // 8 waves per block
constexpr int WAVES_TOTAL = BLOCKS * WPB;      // 8192

// Finisher pass geometry: 50000 f32 = 12500 float4
constexpr int N4    = 12500;
constexpr int FB    = 12;                      // burst depth (48 VGPR)
constexpr int CAP   = 1024;                    // candidate cap (measured nL ~30)
constexpr int BINSHIFT = 20;                   // s<=1.0 -> bin <= 0x3F8 < 1024

// ---------------------------------------------------------------------------
// Single fused kernel.
// Phase 1 (all blocks): cosine scores (math byte-identical to rounds 3-8,
//   measured at the 153.6MB HBM floor). Cross-block-visible writes use
//   RELAXED AGENT-scope atomic stores => write-through (sc1) past the
//   non-coherent per-XCD L2, with NO cache-maintenance ops. (Round-4 lesson:
//   acq_rel/threadfence per block = buffer_wbl2 storm = 8x slowdown.)
// Ticket: s_waitcnt vmcnt(0) + relaxed fetch_add. The block drawing ticket
//   BLOCKS-1 is provably last (every other block's write-through stores
//   drained before its increment) => NO spinning, deadlock-free.
// Finisher (winner block only): ONE acquire load (single buffer_inv -> its
//   L1/L2 drop any stale lines), then plain cached reads are coherent.
//   Then round-8's validated histogram radix-select + epilogue.
// ---------------------------------------------------------------------------
__global__ __launch_bounds__(THREADS)
void k_all(const float* __restrict__ v,
           const float* __restrict__ n_feats,
           const float* __restrict__ n_answ,
           const float* __restrict__ o,
           const float* __restrict__ temp_vid,
           u32*   __restrict__ counter,   // zeroed by 8B memset each call
           u64*   __restrict__ s64,       // 25000 u64 = score pairs
           float* __restrict__ part,      // 1024 exp-partials
           float* __restrict__ out)
{
    const int tid  = threadIdx.x;
    const int lane = tid & 63;
    const int wib  = tid >> 6;

    __shared__ float wsum[WPB];
    __shared__ u32   tksh;
    // finisher storage; Lbuf (8KB, u64-aligned) is overlaid by hist+scan bufs
    __shared__ u64   Lbuf[CAP];
    __shared__ float redA[THREADS], redB[THREADS], redC[THREADS];
    __shared__ float oiash[OD];
    __shared__ float topw[TOPK];
    __shared__ int   topi[TOPK];
    __shared__ u32   ctrL;
    __shared__ int   b1sh;
    __shared__ float zsh;

    // ---------------- phase 1: scores + exp partials ----------------
    {
        const int gwave = blockIdx.x * WPB + wib;
        const float4* v4 = reinterpret_cast<const float4*>(v);
        const float4 va = v4[lane];
        const float4 vb = v4[lane + 64];
        const float4 vc = v4[lane + 128];

        float vsq = 0.f;
        vsq = fmaf(va.x, va.x, vsq); vsq = fmaf(va.y, va.y, vsq);
        vsq = fmaf(va.z, va.z, vsq); vsq = fmaf(va.w, va.w, vsq);
        vsq = fmaf(vb.x, vb.x, vsq); vsq = fmaf(vb.y, vb.y, vsq);
        vsq = fmaf(vb.z, vb.z, vsq); vsq = fmaf(vb.w, vb.w, vsq);
        vsq = fmaf(vc.x, vc.x, vsq); vsq = fmaf(vc.y, vc.y, vsq);
        vsq = fmaf(vc.z, vc.z, vsq); vsq = fmaf(vc.w, vc.w, vsq);
        #pragma unroll
        for (int off = 32; off; off >>= 1) vsq += __shfl_xor(vsq, off);
        const float inv_vn = 1.0f / fmaxf(sqrtf(vsq), 1e-12f);

        float esum = 0.f;
        for (int r = 2 * gwave; r < N; r += 2 * WAVES_TOTAL) {
            // N is even: r+1 < N always
            const float4* f0 = reinterpret_cast<const float4*>(n_feats + (size_t)r * D);
            const float4* f1 = reinterpret_cast<const float4*>(n_feats + (size_t)(r + 1) * D);
            const float4 a0 = f0[lane];
            const float4 a1 = f0[lane + 64];
            const float4 a2 = f0[lane + 128];
            const float4 b0 = f1[lane];
            const float4 b1 = f1[lane + 64];
            const float4 b2 = f1[lane + 128];

            float dA = 0.f, nA = 0.f, dB = 0.f, nB = 0.f;
            dA = fmaf(a0.x, va.x, dA); nA = fmaf(a0.x, a0.x, nA);
            dB = fmaf(b0.x, va.x, dB); nB = fmaf(b0.x, b0.x, nB);
            dA = fmaf(a0.y, va.y, dA); nA = fmaf(a0.y, a0.y, nA);
            dB = fmaf(b0.y, va.y, dB); nB = fmaf(b0.y, b0.y, nB);
            dA = fmaf(a0.z, va.z, dA); nA = fmaf(a0.z, a0.z, nA);
            dB = fmaf(b0.z, va.z, dB); nB = fmaf(b0.z, b0.z, nB);
            dA = fmaf(a0.w, va.w, dA); nA = fmaf(a0.w, a0.w, nA);
            dB = fmaf(b0.w, va.w, dB); nB = fmaf(b0.w, b0.w, nB);
            dA = fmaf(a1.x, vb.x, dA); nA = fmaf(a1.x, a1.x, nA);
            dB = fmaf(b1.x, vb.x, dB); nB = fmaf(b1.x, b1.x, nB);
            dA = fmaf(a1.y, vb.y, dA); nA = fmaf(a1.y, a1.y, nA);
            dB = fmaf(b1.y, vb.y, dB); nB = fmaf(b1.y, b1.y, nB);
            dA = fmaf(a1.z, vb.z, dA); nA = fmaf(a1.z, a1.z, nA);
            dB = fmaf(b1.z, vb.z, dB); nB = fmaf(b1.z, b1.z, nB);
            dA = fmaf(a1.w, vb.w, dA); nA = fmaf(a1.w, a1.w, nA);
            dB = fmaf(b1.w, vb.w, dB); nB = fmaf(b1.w, b1.w, nB);
            dA = fmaf(a2.x, vc.x, dA); nA = fmaf(a2.x, a2.x, nA);
            dB = fmaf(b2.x, vc.x, dB); nB = fmaf(b2.x, b2.x, nB);
            dA = fmaf(a2.y, vc.y, dA); nA = fmaf(a2.y, a2.y, nA);
            dB = fmaf(b2.y, vc.y, dB); nB = fmaf(b2.y, b2.y, nB);
            dA = fmaf(a2.z, vc.z, dA); nA = fmaf(a2.z, a2.z, nA);
            dB = fmaf(b2.z, vc.z, dB); nB = fmaf(b2.z, b2.z, nB);
            dA = fmaf(a2.w, vc.w, dA); nA = fmaf(a2.w, a2.w, nA);
            dB = fmaf(b2.w, vc.w, dB); nB = fmaf(b2.w, b2.w, nB);

            #pragma unroll
            for (int off = 32; off; off >>= 1) {
                dA += __shfl_xor(dA, off);
                nA += __shfl_xor(nA, off);
                dB += __shfl_xor(dB, off);
                nB += __shfl_xor(nB, off);
            }

            float sA = dA * inv_vn / fmaxf(sqrtf(nA), 1e-12f);
            sA = fminf(fmaxf(sA, 0.f), 1.f);
            float sB = dB * inv_vn / fmaxf(sqrtf(nB), 1e-12f);
            sB = fminf(fmaxf(sB, 0.f), 1.f);
            if (lane == 0) {
                const u64 sv = (u64)__float_as_uint(sA) |
                               ((u64)__float_as_uint(sB) << 32);
                // relaxed agent store = write-through, no cache maintenance
                __hip_atomic_store(&s64[r >> 1], sv,
                                   __ATOMIC_RELAXED, __HIP_MEMORY_SCOPE_AGENT);
            }
            esum += expf(sA) + expf(sB);
        }

        if (lane == 0) wsum[wib] = esum;
        __syncthreads();
        if (tid == 0) {
            float t = 0.f;
            #pragma unroll
            for (int w = 0; w < WPB; ++w) t += wsum[w];
            __hip_atomic_store(reinterpret_cast<u32*>(&part[blockIdx.x]),
                               __float_as_uint(t),
                               __ATOMIC_RELAXED, __HIP_MEMORY_SCOPE_AGENT);
        }
    }

    // ---------------- ticket (no spin, no fences) ----------------
    asm volatile("s_waitcnt vmcnt(0)" ::: "memory");  // drain write-throughs
    __syncthreads();
    if (tid == 0)
        tksh = __hip_atomic_fetch_add(counter, 1u,
                                      __ATOMIC_RELAXED, __HIP_MEMORY_SCOPE_AGENT);
    __syncthreads();
    if (tksh != (u32)(BLOCKS - 1)) return;   // everyone but the last retires

    // single acquire: invalidates this CU/XCD's caches -> plain reads coherent
    (void)__hip_atomic_load(counter, __ATOMIC_ACQUIRE, __HIP_MEMORY_SCOPE_AGENT);
    __syncthreads();

    // ---------------- finish phase (winner block, 512 threads) -----------
    u32* hh = reinterpret_cast<u32*>(Lbuf);        // hist  [0..1023]
    u32* ss = hh + 1024;                           // scan  [0..1023]

    for (int i = tid; i < 1024; i += THREADS) hh[i] = 0u;
    if (tid == 0) { ctrL = 0; b1sh = 0; }
    __syncthreads();

    const float4* s4 = reinterpret_cast<const float4*>(s64);

    // pass 1: histogram of nonzero score bits >> 20 (burst-loaded)
    for (int base = 0; base < 12288; base += FB * THREADS) {   // 2 rounds
        float4 r[FB];
        #pragma unroll
        for (int j = 0; j < FB; ++j) r[j] = s4[base + tid + j * THREADS];
        #pragma unroll
        for (int j = 0; j < FB; ++j) {
            u32 b;
            b = __float_as_uint(r[j].x); if (b) atomicAdd(&hh[b >> BINSHIFT], 1u);
            b = __float_as_uint(r[j].y); if (b) atomicAdd(&hh[b >> BINSHIFT], 1u);
            b = __float_as_uint(r[j].z); if (b) atomicAdd(&hh[b >> BINSHIFT], 1u);
            b = __float_as_uint(r[j].w); if (b) atomicAdd(&hh[b >> BINSHIFT], 1u);
        }
    }
    if (tid < N4 - 12288) {
        const float4 rt = s4[12288 + tid];
        u32 b;
        b = __float_as_uint(rt.x); if (b) atomicAdd(&hh[b >> BINSHIFT], 1u);
        b = __float_as_uint(rt.y); if (b) atomicAdd(&hh[b >> BINSHIFT], 1u);
        b = __float_as_uint(rt.z); if (b) atomicAdd(&hh[b >> BINSHIFT], 1u);
        b = __float_as_uint(rt.w); if (b) atomicAdd(&hh[b >> BINSHIFT], 1u);
    }
    __syncthreads();

    // suffix scan (ping-pong) -> crossing bin b1 (cum count >= 25)
    {
        u32* src = hh;
        u32* dst = ss;
        for (int st = 1; st < 1024; st <<= 1) {
            for (int i = tid; i < 1024; i += THREADS)
                dst[i] = src[i] + ((i + st < 1024) ? src[i + st] : 0u);
            __syncthreads();
            u32* t_ = src; src = dst; dst = t_;
        }
        for (int i = tid; i < 1024; i += THREADS)
            if (src[i] >= (u32)TOPK && (i == 1023 || src[i + 1] < (u32)TOPK))
                b1sh = i;                           // exactly one thread
    }
    __syncthreads();
    const int b1 = b1sh;
    __syncthreads();   // all scan reads done before Lbuf is overwritten

    // pass 2: compact keys with bin >= b1 (cache-hot reads)
    // key = (valbits<<32)|(~idx): value desc, ties -> lower index (jax order)
    auto append = [&](u32 b, int e) {
        if (b && (int)(b >> BINSHIFT) >= b1) {
            const u32 p = atomicAdd(&ctrL, 1u);
            if (p < (u32)CAP)
                Lbuf[p] = ((u64)b << 32) | (u64)(0xFFFFFFFFu - (u32)e);
        }
    };
    for (int base = 0; base < 12288; base += FB * THREADS) {
        float4 r[FB];
        #pragma unroll
        for (int j = 0; j < FB; ++j) r[j] = s4[base + tid + j * THREADS];
        #pragma unroll
        for (int j = 0; j < FB; ++j) {
            const int e = (base + tid + j * THREADS) * 4;
            append(__float_as_uint(r[j].x), e + 0);
            append(__float_as_uint(r[j].y), e + 1);
            append(__float_as_uint(r[j].z), e + 2);
            append(__float_as_uint(r[j].w), e + 3);
        }
    }
    if (tid < N4 - 12288) {
        const float4 rt = s4[12288 + tid];
        const int e = (12288 + tid) * 4;
        append(__float_as_uint(rt.x), e + 0);
        append(__float_as_uint(rt.y), e + 1);
        append(__float_as_uint(rt.z), e + 2);
        append(__float_as_uint(rt.w), e + 3);
    }
    __syncthreads();

    // rank-sort L (unique keys -> unique ranks); nL measured ~30 << CAP
    const int nL = (int)((ctrL < (u32)CAP) ? ctrL : (u32)CAP);
    for (int i = tid; i < nL; i += THREADS) {
        const u64 ki = Lbuf[i];
        int rk = 0;
        for (int j = 0; j < nL; ++j) rk += (Lbuf[j] > ki);
        if (rk < TOPK) {
            topw[rk] = expf(__uint_as_float((u32)(ki >> 32)));
            topi[rk] = (int)(0xFFFFFFFFu - (u32)(ki & 0xFFFFFFFFu));
        }
    }
    __syncthreads();

    // Z = deterministic tree over part[1024]
    redA[tid] = part[tid] + part[tid + THREADS >= 1024 ? tid : tid];  // placeholder avoided below
    // (1024 partials, 512 threads -> 2 each)
    redA[tid] = part[tid] + part[tid + 512];
    __syncthreads();
    for (int s = 256; s > 0; s >>= 1) {
        if (tid < s) redA[tid] += redA[tid + s];
        __syncthreads();
    }
    if (tid == 0) zsh = redA[0];
    __syncthreads();

    // epilogue: oia gather + 3 dots.  attention_j = exp(s_j)/Z * 2*sigmoid(t)
    const float gate  = 2.f / (1.f + expf(-temp_vid[0]));
    const float scale = gate / zsh;
    if (tid < OD) {
        float acc = 0.f;
        #pragma unroll
        for (int j = 0; j < TOPK; ++j)
            acc = fmaf(topw[j] * scale, n_answ[(size_t)topi[j] * OD + tid], acc);
        oiash[tid] = acc;
    }
    __syncthreads();
    redA[tid] = (tid < OD) ? oiash[tid] * o[tid]          : 0.f;
    redB[tid] = (tid < OD) ? oiash[tid] * o[OD + tid]     : 0.f;
    redC[tid] = (tid < OD) ? oiash[tid] * o[2 * OD + tid] : 0.f;
    __syncthreads();
    for (int s = 256; s > 0; s >>= 1) {
        if (tid < s) {
            redA[tid] += redA[tid + s];
            redB[tid] += redB[tid + s];
            redC[tid] += redC[tid + s];
        }
        __syncthreads();
    }
    if (tid == 0) { out[0] = redA[0]; out[1] = redB[0]; out[2] = redC[0]; }
}

// ---------------------------------------------------------------------------
extern "C" void kernel_launch(void* const* d_in, const int* in_sizes, int n_in,
                              void* d_out, int out_size, void* d_ws, size_t ws_size,
                              hipStream_t stream)
{
    // setup_inputs order:
    // 0 v, 1 n_feats, 2 aud, 3 n_auds, 4 ocr, 5 n_ocrs, 6 o, 7 n_answ,
    // 8 temp_vid, 9 temp_aud, 10 temp_ocr
    const float* v        = (const float*)d_in[0];
    const float* n_feats  = (const float*)d_in[1];
    const float* o        = (const float*)d_in[6];
    const float* n_answ   = (const float*)d_in[7];
    const float* temp_vid = (const float*)d_in[8];
    // aud/ocr branches are multiplied by exactly 0.0 in the reference -> skipped.
    float* out = (float*)d_out;

    char* ws = (char*)d_ws;
    u32*   counter = (u32*)ws;                    // 4 B, zeroed each call
    u64*   s64     = (u64*)(ws + 256);            // 25000 u64 = 200000 B
    float* part    = (float*)(ws + 256 + 200704); // 1024 f32

    hipMemsetAsync(counter, 0, 64, stream);       // async, graph-capturable
    k_all<<<BLOCKS, THREADS, 0, stream>>>(v, n_feats, n_answ, o, temp_vid,
                                          counter, s64, part, out);
}